// Round 12
// baseline (79.262 us; speedup 1.0000x reference)
//
#include <hip/hip_runtime.h>
#include <math.h>

#define BB 16
#define PP 4096
#define TT 1024
#define NC 12              // 12x12 cells of size 5.5 (> RADIUS: 3x3 coverage robust)
#define NCELL (NC * NC)    // 144
#define NBUK (NCELL * 4)   // 576 buckets = cell x class
#define CSCALE 0.181818187f // 1/5.5
#define LIMKEY 0x41C80FFFu  // key <= this <=> quantized d2 <= 25.0f

// Phase 0 (32 blocks x 1024): per-batch LDS bucket sort.
// Blocks 0-15: preds of batch b -> sorted sx/sy/spo + packed CSR (off | cnt<<16).
// Blocks 16-31: targets of batch b -> sorted tx/ty + tinfo ((cls<<16)|cell).
// LDS atomics only (R6 lesson: global atomic slot alloc = 160 us).
__global__ __launch_bounds__(1024) void build_kernel(const float* __restrict__ pred,
                                                     const float* __restrict__ gt,
                                                     float* __restrict__ sx,
                                                     float* __restrict__ sy,
                                                     unsigned* __restrict__ spo,
                                                     float* __restrict__ tx,
                                                     float* __restrict__ ty,
                                                     unsigned* __restrict__ tinfo,
                                                     unsigned* __restrict__ csr) {
    __shared__ unsigned hist[NBUK], scn[NBUK], cur[NBUK];
    const int tid = threadIdx.x;

    if (blockIdx.x < 16) {
        const int b = blockIdx.x;
        if (tid < NBUK) hist[tid] = 0;
        __syncthreads();

        // 4 pred triples per thread via 3x float4 (unpack validated in R11)
        const float4* src = (const float4*)(pred + (size_t)b * PP * 3);
        const float4 v0 = src[3 * tid + 0];
        const float4 v1 = src[3 * tid + 1];
        const float4 v2 = src[3 * tid + 2];
        const float pc[4] = {v0.x, v0.w, v1.z, v2.y};
        const float px[4] = {v0.y, v1.x, v1.w, v2.z};
        const float py[4] = {v0.z, v1.y, v2.x, v2.w};
        unsigned id[4];
        #pragma unroll
        for (int k = 0; k < 4; ++k) {
            const unsigned cx = (unsigned)(px[k] * CSCALE);
            const unsigned cy = (unsigned)(py[k] * CSCALE);
            id[k] = (unsigned)pc[k] * NCELL + cx * NC + cy;
            atomicAdd(&hist[id[k]], 1u);
        }
        __syncthreads();
        if (tid < NBUK) scn[tid] = hist[tid];
        __syncthreads();
        for (unsigned d = 1; d < NBUK; d <<= 1) {   // inclusive scan, 10 steps
            unsigned v = 0;
            if (tid < NBUK) { v = scn[tid]; if (tid >= d) v += scn[tid - d]; }
            __syncthreads();
            if (tid < NBUK) scn[tid] = v;
            __syncthreads();
        }
        if (tid < NBUK) {
            const unsigned cnt = hist[tid];
            const unsigned off = scn[tid] - cnt;
            cur[tid] = off;
            csr[b * NBUK + tid] = off | (cnt << 16);
        }
        __syncthreads();
        #pragma unroll
        for (int k = 0; k < 4; ++k) {
            const unsigned pos = atomicAdd(&cur[id[k]], 1u);
            sx[(size_t)b * PP + pos]  = px[k];
            sy[(size_t)b * PP + pos]  = py[k];
            spo[(size_t)b * PP + pos] = (unsigned)(tid * 4 + k);   // orig p in batch
        }
    } else {
        const int b = blockIdx.x - 16;
        if (tid < NBUK) hist[tid] = 0;
        __syncthreads();

        const float* g = gt + ((size_t)b * TT + tid) * 3;
        const float c = g[0], x = g[1], y = g[2];
        const unsigned cx = (unsigned)(x * CSCALE);
        const unsigned cy = (unsigned)(y * CSCALE);
        const unsigned cell = cx * NC + cy;
        const unsigned id = (unsigned)c * NCELL + cell;
        atomicAdd(&hist[id], 1u);
        __syncthreads();
        if (tid < NBUK) scn[tid] = hist[tid];
        __syncthreads();
        for (unsigned d = 1; d < NBUK; d <<= 1) {
            unsigned v = 0;
            if (tid < NBUK) { v = scn[tid]; if (tid >= d) v += scn[tid - d]; }
            __syncthreads();
            if (tid < NBUK) scn[tid] = v;
            __syncthreads();
        }
        if (tid < NBUK) cur[tid] = scn[tid] - hist[tid];
        __syncthreads();
        const unsigned pos = atomicAdd(&cur[id], 1u);
        tx[(size_t)b * TT + pos]    = x;
        ty[(size_t)b * TT + pos]    = y;
        tinfo[(size_t)b * TT + pos] = ((unsigned)c << 16) | cell;
    }
}

// Phase 1 (64 blocks x 256): one thread per sorted target; scan the 3x3 cell
// neighborhood of its (class, cell) bucket. dy-neighbors are CSR-contiguous
// (bucket id = cls*144 + cx*13.. cx*12+cy) -> one range per dx. Packed key
// (d2_bits & ~0xFFF) | orig_p -> argmin + lowest-p tie-break via u32 min.
// Sorted-target order makes wave gathers cell-coherent. part slot per sorted
// position (set semantics: target identity irrelevant for tp).
__global__ __launch_bounds__(256) void match_kernel(const float* __restrict__ sx,
                                                    const float* __restrict__ sy,
                                                    const unsigned* __restrict__ spo,
                                                    const float* __restrict__ tx,
                                                    const float* __restrict__ ty,
                                                    const unsigned* __restrict__ tinfo,
                                                    const unsigned* __restrict__ csr,
                                                    unsigned* __restrict__ part) {
    const int b = blockIdx.x >> 2;
    const int i = ((blockIdx.x & 3) << 8) + threadIdx.x;   // sorted target index

    const unsigned info = tinfo[(size_t)b * TT + i];
    const unsigned cls  = info >> 16;
    const unsigned cell = info & 0xFFFFu;
    const float x = tx[(size_t)b * TT + i];
    const float y = ty[(size_t)b * TT + i];

    const unsigned cx = (cell * 5462u) >> 16;   // exact /12 for cell < 144
    const unsigned cy = cell - cx * NC;
    const int x0 = cx ? -1 : 0, x1 = (cx < NC - 1) ? 1 : 0;
    const int y0 = cy ? -1 : 0, y1 = (cy < NC - 1) ? 1 : 0;
    const unsigned base = cls * NCELL + cell;
    const unsigned* csrb = csr + b * NBUK;
    const float* sxb = sx + (size_t)b * PP;
    const float* syb = sy + (size_t)b * PP;
    const unsigned* spob = spo + (size_t)b * PP;

    unsigned best = 0xFFFFFFFFu;
    for (int dx = x0; dx <= x1; ++dx) {
        const unsigned w0 = csrb[(int)base + dx * NC + y0];
        const unsigned w2 = csrb[(int)base + dx * NC + y1];
        unsigned s = w0 & 0xFFFFu;
        const unsigned e = (w2 & 0xFFFFu) + (w2 >> 16);
        for (; s < e; ++s) {
            const float ddx = sxb[s] - x;
            const float ddy = syb[s] - y;
            const float d2 = fmaf(ddx, ddx, ddy * ddy);
            const unsigned kk = (__float_as_uint(d2) & 0xFFFFF000u) | spob[s];
            best = min(best, kk);
        }
    }
    part[(size_t)b * TT + i] = best;
}

// Phase 2: single block 1024 thr: radius-filter keys, bitmap distinct hit preds
// (8 KB LDS), popcount -> tp, F1 scalar.
__global__ __launch_bounds__(1024) void tail_kernel(const unsigned* __restrict__ part,
                                                    float* __restrict__ out) {
    __shared__ unsigned bm[BB * PP / 32];   // 2048 words
    for (int i = threadIdx.x; i < BB * PP / 32; i += 1024) bm[i] = 0;
    __syncthreads();

    #pragma unroll 4
    for (int i = threadIdx.x; i < BB * TT; i += 1024) {
        const unsigned k = part[i];
        if (k <= LIMKEY) {
            const unsigned g = (unsigned)(i >> 10) * PP + (k & 0xFFFu);
            atomicOr(&bm[g >> 5], 1u << (g & 31));
        }
    }
    __syncthreads();

    int sum = 0;
    for (int i = threadIdx.x; i < BB * PP / 32; i += 1024) sum += __popc(bm[i]);
    for (int off = 32; off; off >>= 1) sum += __shfl_down(sum, off, 64);

    __shared__ int ss[16];
    const int wid  = threadIdx.x >> 6;
    const int lane = threadIdx.x & 63;
    if (lane == 0) ss[wid] = sum;
    __syncthreads();
    if (threadIdx.x == 0) {
        int tp_i = 0;
        for (int w = 0; w < 16; ++w) tp_i += ss[w];
        const float tp = (float)tp_i;
        const float eps = 1e-6f;
        const float fp = (float)(BB * PP) - tp;
        const float fn = (float)(BB * TT) - tp;
        const float precision = (tp + eps) / (tp + eps + fp + eps);
        const float recall    = (tp + eps) / (tp + fn + eps);
        const float f1 = 2.0f * precision * recall / (precision + recall);
        out[0] = 1.0f - f1;
    }
}

extern "C" void kernel_launch(void* const* d_in, const int* in_sizes, int n_in,
                              void* d_out, int out_size, void* d_ws, size_t ws_size,
                              hipStream_t stream) {
    const float* pred = (const float*)d_in[0];  // (B, P, 3): cls, x, y
    const float* gt   = (const float*)d_in[1];  // (B, T, 3)
    float* out = (float*)d_out;

    char* ws = (char*)d_ws;
    float*    sx    = (float*)   (ws + 0);        // 256 KB
    float*    sy    = (float*)   (ws + 262144);   // 256 KB
    unsigned* spo   = (unsigned*)(ws + 524288);   // 256 KB
    float*    tx    = (float*)   (ws + 786432);   // 64 KB
    float*    ty    = (float*)   (ws + 851968);   // 64 KB
    unsigned* tinfo = (unsigned*)(ws + 917504);   // 64 KB
    unsigned* csr   = (unsigned*)(ws + 983040);   // 36 KB
    unsigned* part  = (unsigned*)(ws + 1019904);  // 64 KB

    build_kernel<<<32, 1024, 0, stream>>>(pred, gt, sx, sy, spo, tx, ty, tinfo, csr);
    match_kernel<<<64, 256, 0, stream>>>(sx, sy, spo, tx, ty, tinfo, csr, part);
    tail_kernel<<<1, 1024, 0, stream>>>(part, out);
}